// Round 1
// baseline (1345.183 us; speedup 1.0000x reference)
//
#include <hip/hip_runtime.h>

#define DEV __device__ __forceinline__

typedef __attribute__((ext_vector_type(4))) float f32x4;
typedef __bf16 bf16x8 __attribute__((ext_vector_type(8)));
typedef __attribute__((ext_vector_type(4))) unsigned int uint4v;

DEV unsigned short f2bf(float f) {
  unsigned int u = __float_as_uint(f);
  u += 0x7fffu + ((u >> 16) & 1u);   // round-to-nearest-even
  return (unsigned short)(u >> 16);
}
DEV float bf2f(unsigned short h) { return __uint_as_float(((unsigned int)h) << 16); }

// ---------------- prep: WcatT[o][j] bf16, o<1024, j<1152 ----------------
// j<128  : scale_base[j][o]            (pairs with silu(x_j) in phi)
// j>=128 : scale_sp[i][o]*coef[i][o][c], e=j-128, i=e>>3, c=e&7  (pairs with basis)
__global__ __launch_bounds__(256) void prep_wcat_kernel(
    const float* __restrict__ scale_base, const float* __restrict__ scale_sp,
    const float* __restrict__ coef, unsigned short* __restrict__ WcatT)
{
  int o = blockIdx.x;
  for (int j = threadIdx.x; j < 1152; j += 256) {
    float v;
    if (j < 128) {
      v = scale_base[j * 1024 + o];
    } else {
      int e = j - 128, i = e >> 3, c = e & 7;
      v = scale_sp[i * 1024 + o] * coef[(size_t)(i * 1024 + o) * 8 + c];
    }
    WcatT[(size_t)o * 1152 + j] = f2bf(v);
  }
}

// ---------------- prep: fwT[n][h] = bf16(f_w[h][n]) (LDS tile transpose) ----------------
__global__ __launch_bounds__(256) void prep_fwT_kernel(
    const float* __restrict__ fw, unsigned short* __restrict__ fwT)
{
  __shared__ float tile[64][65];
  int n0 = blockIdx.x * 64, h0 = blockIdx.y * 64;
  for (int e = threadIdx.x; e < 4096; e += 256) {
    int r = e >> 6, c = e & 63;
    tile[r][c] = fw[(size_t)(h0 + r) * 8192 + n0 + c];
  }
  __syncthreads();
  for (int e = threadIdx.x; e < 4096; e += 256) {
    int r = e >> 6, c = e & 63;  // r: n-offset, c: h-offset
    fwT[(size_t)(n0 + r) * 1024 + h0 + c] = f2bf(tile[c][r]);
  }
}

// ---------------- phi: x concat, silu, Cox-de-Boor bases ----------------
// phi row layout (1152 bf16): [silu(x_0..127) | bases(i=0)[0..7] ... bases(i=127)[0..7]]
__global__ void phi_kernel(const float* __restrict__ state, const float* __restrict__ novelU,
                           float* __restrict__ xbuf, unsigned short* __restrict__ phi)
{
  int b = blockIdx.x, i = threadIdx.x;  // 128 threads
  float x = (i < 64) ? state[(size_t)b * 64 + i] : novelU[(size_t)b * 64 + (i - 64)];
  xbuf[(size_t)b * 128 + i] = x;
  float sil = x / (1.0f + expf(-x));
  float t[12];
#pragma unroll
  for (int m = 0; m < 12; m++) t[m] = -1.0f + 0.4f * (float)(m - 3);
  float bb[11];
#pragma unroll
  for (int m = 0; m < 11; m++) bb[m] = (x >= t[m] && x < t[m + 1]) ? 1.0f : 0.0f;
#pragma unroll
  for (int j = 1; j <= 3; j++) {
#pragma unroll
    for (int m = 0; m + j < 11; m++) {
      bb[m] = (x - t[m]) / (t[m + j] - t[m]) * bb[m]
            + (t[m + j + 1] - x) / (t[m + j + 1] - t[m + 1]) * bb[m + 1];
    }
  }
  unsigned short* row = phi + (size_t)b * 1152;
  row[i] = f2bf(sil);
  alignas(16) unsigned short tmp[8];
#pragma unroll
  for (int c = 0; c < 8; c++) tmp[c] = f2bf(bb[c]);
  *(uint4v*)&row[128 + i * 8] = *(const uint4v*)tmp;
}

// ---------------- bf16 MFMA GEMM: C[M][N] = A[M][K] @ BT[N][K]^T (+bias) ----------------
// 128x128 tile, BK=32, 4 waves in 2x2, each wave 64x64 via 4x4 16x16x32 frags.
template<bool OUT_BF16, bool ADD_BIAS>
__global__ __launch_bounds__(256) void gemm_kernel(
    const unsigned short* __restrict__ A, const unsigned short* __restrict__ BT,
    void* __restrict__ Cout, const float* __restrict__ bias,
    int M, int N, int K)
{
  constexpr int LDT = 40;  // 32 + 8 pad (keeps 16B alignment, breaks bank conflicts)
  __shared__ __align__(16) unsigned short As[128 * LDT];
  __shared__ __align__(16) unsigned short Bs[128 * LDT];
  const int tid = threadIdx.x;
  const int m0 = blockIdx.x * 128, n0 = blockIdx.y * 128;
  const int wave = tid >> 6, lane = tid & 63;
  const int wm = (wave >> 1) * 64, wn = (wave & 1) * 64;
  const int lr = lane & 15, kg = lane >> 4;
  f32x4 acc[4][4];
#pragma unroll
  for (int m = 0; m < 4; m++)
#pragma unroll
    for (int n = 0; n < 4; n++) acc[m][n] = (f32x4){0.f, 0.f, 0.f, 0.f};

  for (int kt = 0; kt < K; kt += 32) {
    __syncthreads();  // protect previous iteration's readers
#pragma unroll
    for (int i = 0; i < 2; i++) {
      int c = tid + i * 256;           // 512 16B-chunks per tile
      int row = c >> 2, co = (c & 3) * 8;
      *(uint4v*)&As[row * LDT + co] = *(const uint4v*)&A[(size_t)(m0 + row) * K + kt + co];
      *(uint4v*)&Bs[row * LDT + co] = *(const uint4v*)&BT[(size_t)(n0 + row) * K + kt + co];
    }
    __syncthreads();
    bf16x8 af[4], bfr[4];
#pragma unroll
    for (int m = 0; m < 4; m++)
      af[m] = *(const bf16x8*)&As[(wm + m * 16 + lr) * LDT + kg * 8];
#pragma unroll
    for (int n = 0; n < 4; n++)
      bfr[n] = *(const bf16x8*)&Bs[(wn + n * 16 + lr) * LDT + kg * 8];
#pragma unroll
    for (int m = 0; m < 4; m++)
#pragma unroll
      for (int n = 0; n < 4; n++)
        acc[m][n] = __builtin_amdgcn_mfma_f32_16x16x32_bf16(af[m], bfr[n], acc[m][n], 0, 0, 0);
  }
  // epilogue: C/D layout col=lane&15, row=(lane>>4)*4+reg  [m89/m91-verified]
#pragma unroll
  for (int m = 0; m < 4; m++) {
    int row = m0 + wm + m * 16 + kg * 4;
#pragma unroll
    for (int n = 0; n < 4; n++) {
      int col = n0 + wn + n * 16 + lr;
      float badd = ADD_BIAS ? bias[col] : 0.0f;
#pragma unroll
      for (int r = 0; r < 4; r++) {
        float v = acc[m][n][r] + badd;
        size_t off = (size_t)(row + r) * N + col;
        if (OUT_BF16) ((unsigned short*)Cout)[off] = f2bf(v);
        else          ((float*)Cout)[off] = v;
      }
    }
  }
}

// ---------------- bmm + bias: bias = kan@bias_w + bias_b; out = AB.x + bias ----------------
// 4 b-rows per block (amortizes the 256KB bias_w sweep).
__global__ __launch_bounds__(256) void bmm_kernel(
    const float* __restrict__ xbuf, const unsigned short* __restrict__ kan,
    const float* __restrict__ bias_w, const float* __restrict__ bias_b,
    const float* __restrict__ AB, float* __restrict__ out, float* __restrict__ bias_out)
{
  __shared__ __align__(16) float xs[4][128];
  __shared__ float kf[4][1024];
  __shared__ float red[4][4][64];
  __shared__ float bs[4][64];
  const int tid = threadIdx.x;
  const size_t b0 = (size_t)blockIdx.x * 4;
  for (int e = tid; e < 512; e += 256) { int r = e >> 7, u = e & 127; xs[r][u] = xbuf[(b0 + r) * 128 + u]; }
  for (int e = tid; e < 4096; e += 256) { int r = e >> 10, h = e & 1023; kf[r][h] = bf2f(kan[(b0 + r) * 1024 + h]); }
  __syncthreads();
  {
    const int s = tid & 63, part = tid >> 6;
    float a0 = 0, a1 = 0, a2 = 0, a3 = 0;
    for (int h = part * 256; h < part * 256 + 256; ++h) {
      float w = bias_w[h * 64 + s];
      a0 = fmaf(kf[0][h], w, a0); a1 = fmaf(kf[1][h], w, a1);
      a2 = fmaf(kf[2][h], w, a2); a3 = fmaf(kf[3][h], w, a3);
    }
    red[part][0][s] = a0; red[part][1][s] = a1; red[part][2][s] = a2; red[part][3][s] = a3;
  }
  __syncthreads();
  {
    const int r = tid >> 6, s = tid & 63;
    float v = red[0][r][s] + red[1][r][s] + red[2][r][s] + red[3][r][s] + bias_b[s];
    bs[r][s] = v;
    bias_out[(b0 + r) * 64 + s] = v;
  }
  __syncthreads();
  const int s2 = tid >> 2, q = tid & 3;   // 64 s-values x 4 lanes, groups stay inside a wave
#pragma unroll
  for (int r = 0; r < 4; r++) {
    const float* ABr = AB + ((b0 + r) * 64 + s2) * 128;
    float acc = 0.f;
#pragma unroll
    for (int j = 0; j < 8; j++) {       // 4 lanes cover one 64B line per j
      float4 v  = *(const float4*)&ABr[16 * j + 4 * q];
      float4 xv = *(const float4*)&xs[r][16 * j + 4 * q];
      acc = fmaf(v.x, xv.x, acc); acc = fmaf(v.y, xv.y, acc);
      acc = fmaf(v.z, xv.z, acc); acc = fmaf(v.w, xv.w, acc);
    }
    acc += __shfl_xor(acc, 1);
    acc += __shfl_xor(acc, 2);
    if (q == 0) out[(b0 + r) * 64 + s2] = acc + bs[r][s2];
  }
}

extern "C" void kernel_launch(void* const* d_in, const int* in_sizes, int n_in,
                              void* d_out, int out_size, void* d_ws, size_t ws_size,
                              hipStream_t stream)
{
  const float* novelU     = (const float*)d_in[0];
  const float* state      = (const float*)d_in[1];
  const float* coef       = (const float*)d_in[2];
  const float* scale_base = (const float*)d_in[3];
  const float* scale_sp   = (const float*)d_in[4];
  const float* bias_w     = (const float*)d_in[5];
  const float* bias_b     = (const float*)d_in[6];
  const float* f_w        = (const float*)d_in[7];
  const float* f_b        = (const float*)d_in[8];
  const int B = in_sizes[0] / 64;           // 16384
  float* out_ptr  = (float*)d_out;                     // [B][64]
  float* AB_ptr   = out_ptr + (size_t)B * 64;          // [B][64][128]
  float* bias_ptr = AB_ptr + (size_t)B * 64 * 128;     // [B][64]

  char* ws = (char*)d_ws;
  unsigned short* WcatT = (unsigned short*)ws;                       // 1024*1152*2 = 2359296
  unsigned short* fwT   = (unsigned short*)(ws + 2359296);           // 8192*1024*2 = 16777216
  float*          xbuf  = (float*)(ws + 19136512);                   // B*128*4
  unsigned short* phi   = (unsigned short*)(ws + 19136512 + (size_t)B * 128 * 4);   // B*1152*2
  unsigned short* kan   = (unsigned short*)((char*)phi + (size_t)B * 1152 * 2);     // B*1024*2
  size_t need = 19136512 + (size_t)B * 128 * 4 + (size_t)B * 1152 * 2 + (size_t)B * 1024 * 2;
  if (ws_size < need) return;  // refuse to scribble OOB

  prep_wcat_kernel<<<1024, 256, 0, stream>>>(scale_base, scale_sp, coef, WcatT);
  prep_fwT_kernel<<<dim3(128, 16), 256, 0, stream>>>(f_w, fwT);
  phi_kernel<<<B, 128, 0, stream>>>(state, novelU, xbuf, phi);
  // kan[B][1024] = phi[B][1152] @ Wcat  (bf16 out)
  gemm_kernel<true,  false><<<dim3(B / 128, 1024 / 128), 256, 0, stream>>>(
      phi, WcatT, kan, nullptr, B, 1024, 1152);
  // AB[B][8192] = kan @ f_w + f_b  (fp32 out, straight into d_out)
  gemm_kernel<false, true ><<<dim3(B / 128, 8192 / 128), 256, 0, stream>>>(
      kan, fwT, AB_ptr, f_b, B, 8192, 1024);
  bmm_kernel<<<B / 4, 256, 0, stream>>>(xbuf, kan, bias_w, bias_b, AB_ptr, out_ptr, bias_ptr);
}